// Round 2
// baseline (1595.427 us; speedup 1.0000x reference)
//
#include <hip/hip_runtime.h>
#include <math.h>
#include <stdint.h>

#define Lr 32
#define Hh 128
#define NCELL (Lr * Lr)
#define NEPS 1e-8f
#define WCELL (33 * 256)   // h2 elements per cell (33 KB): 32KB swizzled A + 1KB tail

typedef _Float16 f16;
typedef f16 h2 __attribute__((ext_vector_type(2)));

#define GLOBAL_AS __attribute__((address_space(1)))
#define LDS_AS    __attribute__((address_space(3)))

// End-of-cell barrier: drains the async global->LDS stage (vmcnt) and all
// LDS traffic (lgkmcnt), then syncs. One per cell.
__device__ __forceinline__ void bar_cell() {
    asm volatile("s_waitcnt vmcnt(0) lgkmcnt(0)\n\ts_barrier" ::: "memory");
}

template<int CTRL>
__device__ __forceinline__ float dpp_get(float x) {
    return __int_as_float(__builtin_amdgcn_update_dpp(
        0, __float_as_int(x), CTRL, 0xf, 0xf, true));
}
// DPP ctrl: 0xB1 = quad_perm[1,0,3,2] (xor1), 0x4E = quad_perm[2,3,0,1] (xor2),
//           0x141 = row_half_mirror, 0x140 = row_mirror

__device__ __forceinline__ float rlane(float x, int l) {
    return __int_as_float(__builtin_amdgcn_readlane(__float_as_int(x), l));
}

__device__ __forceinline__ float dot2(h2 a, h2 b, float c) {
    return __builtin_amdgcn_fdot2(a, b, c, false);   // v_dot2_f32_f16
}

__device__ __forceinline__ h2 bch2(uint32_t v) {
    union { uint32_t u; h2 h; } cv; cv.u = v; return cv.h;
}

__device__ __forceinline__ float fast_tanh(float x) {
    x = fminf(9.f, fmaxf(-9.f, x));
    const float e = __expf(2.f * x);
    return 1.f - 2.f / (e + 1.f);
}

__device__ __forceinline__ int cell_of(int s) {
    const int i = s >> 5, jj = s & 31;
    const int c = (i & 1) ? (Lr - 1 - jj) : jj;
    return i * Lr + c;
}

// W1[cell][k][m] (fp32, k<128, m<130) -> Wt[cell], 33 KB, laid out for the
// rnn kernel's LDS image (global layout == linear LDS image, m173 pattern):
//   region A (32 KB): thread t (k=t>>1, half=t&1) owns pairs q=0..31
//     (pair q = W-elems (2p,2p+1), p = half*33+q) as 8 16B chunks; chunk q4
//     stored at phys chunk q4^(t&7)  -> conflict-free ds_read_b128 (T2).
//   region B (1 KB): pair q=32 of thread t at h2 slot 8192+t.
__global__ __launch_bounds__(256)
void transpose_w(const float* __restrict__ W1, h2* __restrict__ Wt) {
    __shared__ __align__(16) f16 tile[Hh * 132];
    const int cell = blockIdx.x;
    const float* src = W1 + (size_t)cell * (Hh * 130);
    for (int idx = threadIdx.x; idx < Hh * 130; idx += 256) {
        const int kk = idx / 130, m = idx - kk * 130;
        tile[kk * 132 + m] = (f16)src[idx];
    }
    for (int idx = threadIdx.x; idx < Hh * 2; idx += 256)
        tile[(idx >> 1) * 132 + 130 + (idx & 1)] = (f16)0.f;
    __syncthreads();
    h2* dst = Wt + (size_t)cell * WCELL;
    const h2* t2 = (const h2*)tile;   // row stride 66 h2; pair p = elems 2p,2p+1
    for (int idx = threadIdx.x; idx < 8192; idx += 256) {
        const int tt = idx >> 5, q = idx & 31;
        const int kk = tt >> 1, p = (tt & 1) * 33 + q;
        const int q4 = q >> 2, qj = q & 3;
        dst[tt * 32 + ((q4 ^ (tt & 7)) << 2) + qj] = t2[kk * 66 + p];
    }
    if (threadIdx.x < 256) {
        const int tt = threadIdx.x;
        const int kk = tt >> 1, p = (tt & 1) * 33 + 32;
        dst[8192 + tt] = t2[kk * 66 + p];
    }
}

// 256 blocks x 2 batch elements, 1 block/CU. 256 threads: lane pair (2k,2k+1)
// owns output k; half=t&1 is the m-split. Weights stream through an LDS
// double-buffer filled by global_load_lds (no register-allocator involvement
// -> prefetch cannot be sunk/spilled, unlike rounds 0-1 where VGPR=48/60
// proved the wA/wB register prefetch was defeated). One barrier per cell,
// vmcnt(0) folded into it (stage has a full cell of latency cover).
__global__ __launch_bounds__(256, 1)
void rnn2d(const float* __restrict__ samples,
           const h2* __restrict__ Wt,
           const float* __restrict__ b1,
           const float* __restrict__ Wf,
           const float* __restrict__ bfv,
           float* __restrict__ out)
{
    __shared__ __align__(16) h2 wbuf[2][WCELL];     // 67.6 KB weight double-buffer
    // inp slots per [e][parity]: pairs 0..32 at 0..32, pairs 33..65 at 36..68
    __shared__ __align__(16) h2  inp[2][2][72];
    __shared__ __align__(16) f16 hvh[2][Lr * Hh];   // vertical hidden, 16 KB
    __shared__ float smp2[2][NCELL];
    __shared__ float bfs[NCELL];
    __shared__ float fp_[2][2][4];                  // head partials [e][parity][wave]
    __shared__ float lpb[4];

    const int t    = threadIdx.x;
    const int k    = t >> 1;
    const int half = t & 1;
    const int w    = t >> 6;
    const int lane16 = (t & 63) << 4;
    const int b0   = blockIdx.x * 2;

    {
        f16* z1 = (f16*)inp;
        for (int idx = t; idx < 2 * 2 * 72 * 2; idx += 256) z1[idx] = (f16)0.f;
        f16* z2 = (f16*)hvh;
        for (int idx = t; idx < 2 * Lr * Hh; idx += 256) z2[idx] = (f16)0.f;
        for (int idx = t; idx < NCELL; idx += 256) {
            smp2[0][idx] = samples[(size_t)b0 * NCELL + idx];
            smp2[1][idx] = samples[(size_t)(b0 + 1) * NCELL + idx];
            bfs[idx] = bfv[idx];
        }
        if (t == 0) {           // cell 0 input: xh=xv=0 -> pair0 = (0, 2)
            h2 x0; x0.x = (f16)0.f; x0.y = (f16)2.f;
            inp[0][0][0] = x0;
            inp[1][0][0] = x0;
        }
    }
    float lp = 0.f;
    float bvA, bvB, wvA, wvB;

// async-stage cell S's 33KB weight block into wbuf[P]; wave w copies rows
// r = w, w+4, ... (1 KB each: 64 lanes x 16B, linear dest).
#define STAGE(S, P)                                                         \
    {                                                                       \
        const int cc_ = cell_of(S);                                         \
        const char* gb_ = (const char*)(Wt + (size_t)cc_ * WCELL);          \
        for (int r_ = w; r_ < 33; r_ += 4) {                                \
            const char* gp_ = gb_ + r_ * 1024 + lane16;                     \
            __builtin_amdgcn_global_load_lds(                               \
                (const GLOBAL_AS uint32_t*)gp_,                             \
                (LDS_AS uint32_t*)&wbuf[P][r_ * 256], 16, 0, 0);            \
        }                                                                   \
    }

#define LOADF(S, BV, WV)                                                    \
    {                                                                       \
        const int cc_ = cell_of(S);                                         \
        BV = 2.f * b1[cc_ * Hh + k];                                        \
        WV = Wf[cc_ * Hh + k];                                              \
    }

#define PROCESS(S, Q, BV, WV)                                               \
    {                                                                       \
        const int i_ = (S) >> 5, j_ = (S) & 31;                             \
        const int c_ = (i_ & 1) ? (Lr - 1 - j_) : j_;                       \
        const int sn_ = ((S) + 1 < NCELL) ? (S) + 1 : (S);                  \
        const int in_ = sn_ >> 5, jn_ = sn_ & 31;                           \
        const int cn_ = (in_ & 1) ? (Lr - 1 - jn_) : jn_;                   \
        const float hvn0 = (float)hvh[0][cn_ * Hh + k];                     \
        const float hvn1 = (float)hvh[1][cn_ * Hh + k];                     \
        /* deferred lp tail for cell S-1: one lane per wave, one log each */\
        if (((t & 63) == 4) && (S) > 0) {                                   \
            const int e_ = w >> 1, r_ = w & 1;                              \
            const int cp_ = cell_of((S) - 1);                               \
            const float z_ = fp_[e_][Q][0] + fp_[e_][Q][1]                  \
                           + fp_[e_][Q][2] + fp_[e_][Q][3] + bfs[cp_];      \
            const float xh_ = 1.f / (1.f + __expf(-z_));                    \
            const float m_ = smp2[e_][cp_];                                 \
            lp += (r_ == 0) ? __logf(xh_ + NEPS) * m_                       \
                            : __logf(1.f - xh_ + NEPS) * (1.f - m_);        \
        }                                                                   \
        /* preload this cell's input vectors (b128 broadcast reads) */      \
        h2 x0[33], x1[33];                                                  \
        {                                                                   \
            const uint4* p0 = (const uint4*)&inp[0][Q][half * 36];          \
            const uint4* p1 = (const uint4*)&inp[1][Q][half * 36];          \
            _Pragma("unroll")                                               \
            for (int r_ = 0; r_ < 8; ++r_) {                                \
                const uint4 v0 = p0[r_]; const uint4 v1 = p1[r_];           \
                x0[4*r_+0] = bch2(v0.x); x0[4*r_+1] = bch2(v0.y);           \
                x0[4*r_+2] = bch2(v0.z); x0[4*r_+3] = bch2(v0.w);           \
                x1[4*r_+0] = bch2(v1.x); x1[4*r_+1] = bch2(v1.y);           \
                x1[4*r_+2] = bch2(v1.z); x1[4*r_+3] = bch2(v1.w);           \
            }                                                               \
            x0[32] = inp[0][Q][half * 36 + 32];                             \
            x1[32] = inp[1][Q][half * 36 + 32];                             \
        }                                                                   \
        /* dot: 8 swizzled b128 weight chunks + 1 tail h2, 4-acc chains */  \
        const char* wbyte = (const char*)&wbuf[Q][0] + (t << 7);            \
        float a0[4] = {0.f,0.f,0.f,0.f}, a1[4] = {0.f,0.f,0.f,0.f};         \
        _Pragma("unroll")                                                   \
        for (int q4 = 0; q4 < 8; ++q4) {                                    \
            const uint4 v = *(const uint4*)(wbyte + ((q4 ^ (t & 7)) << 4)); \
            const h2 w0 = bch2(v.x), w1 = bch2(v.y);                        \
            const h2 w2 = bch2(v.z), w3 = bch2(v.w);                        \
            a0[0] = dot2(w0, x0[4*q4+0], a0[0]);                            \
            a1[0] = dot2(w0, x1[4*q4+0], a1[0]);                            \
            a0[1] = dot2(w1, x0[4*q4+1], a0[1]);                            \
            a1[1] = dot2(w1, x1[4*q4+1], a1[1]);                            \
            a0[2] = dot2(w2, x0[4*q4+2], a0[2]);                            \
            a1[2] = dot2(w2, x1[4*q4+2], a1[2]);                            \
            a0[3] = dot2(w3, x0[4*q4+3], a0[3]);                            \
            a1[3] = dot2(w3, x1[4*q4+3], a1[3]);                            \
        }                                                                   \
        {                                                                   \
            const h2 wt_ = wbuf[Q][8192 + t];                               \
            a0[0] = dot2(wt_, x0[32], a0[0]);                               \
            a1[0] = dot2(wt_, x1[32], a1[0]);                               \
        }                                                                   \
        float s0 = (a0[0] + a0[1]) + (a0[2] + a0[3]);                       \
        float s1 = (a1[0] + a1[1]) + (a1[2] + a1[3]);                       \
        s0 += dpp_get<0xB1>(s0);   /* pair combine: full 130-dot */         \
        s1 += dpp_get<0xB1>(s1);                                            \
        const float h0 = fast_tanh(s0 + (BV));                              \
        const float h1 = fast_tanh(s1 + (BV));                              \
        /* head: per-wave sum of h[k]*wf[k] (pair-duplicated, skip xor1) */ \
        float f0 = h0 * (WV), f1 = h1 * (WV);                               \
        f0 += dpp_get<0x4E>(f0);  f1 += dpp_get<0x4E>(f1);                  \
        f0 += dpp_get<0x141>(f0); f1 += dpp_get<0x141>(f1);                 \
        f0 += dpp_get<0x140>(f0); f1 += dpp_get<0x140>(f1);                 \
        f0 = f0 + rlane(f0, 16) + rlane(f0, 32) + rlane(f0, 48);            \
        f1 = f1 + rlane(f1, 16) + rlane(f1, 32) + rlane(f1, 48);            \
        if ((S) + 1 < NCELL) {                                              \
            const float v0 = ((jn_ == 0) ? 0.f : h0)                        \
                           + ((cn_ == c_) ? h0 : hvn0);                     \
            const float v1 = ((jn_ == 0) ? 0.f : h1)                        \
                           + ((cn_ == c_) ? h1 : hvn1);                     \
            const float v0p = dpp_get<0x4E>(v0);  /* partner k's value */   \
            const float v1p = dpp_get<0x4E>(v1);                            \
            if ((t & 3) == 0) {                                             \
                const int p_ = (t >> 2) + 1;                                \
                const int sl_ = (p_ < 33) ? p_ : p_ + 3;                    \
                h2 u0; u0.x = (f16)v0; u0.y = (f16)v0p;                     \
                h2 u1; u1.x = (f16)v1; u1.y = (f16)v1p;                     \
                inp[0][(Q) ^ 1][sl_] = u0;                                  \
                inp[1][(Q) ^ 1][sl_] = u1;                                  \
            }                                                               \
            if (t == 0) {                                                   \
                const float xh0 = (jn_ == 0) ? 0.f : smp2[0][i_ * Lr + c_]; \
                const float xv0 = (in_ == 0) ? 0.f                          \
                                             : smp2[0][(in_ - 1) * Lr + cn_]; \
                const float xh1 = (jn_ == 0) ? 0.f : smp2[1][i_ * Lr + c_]; \
                const float xv1 = (in_ == 0) ? 0.f                          \
                                             : smp2[1][(in_ - 1) * Lr + cn_]; \
                h2 x0_; x0_.x = (f16)(xh0 + xv0); x0_.y = (f16)(2.f - xh0 - xv0); \
                h2 x1_; x1_.x = (f16)(xh1 + xv1); x1_.y = (f16)(2.f - xh1 - xv1); \
                inp[0][(Q) ^ 1][0] = x0_;                                   \
                inp[1][(Q) ^ 1][0] = x1_;                                   \
            }                                                               \
        }                                                                   \
        hvh[0][c_ * Hh + k] = (f16)h0;  /* k-partitioned: race-free */      \
        hvh[1][c_ * Hh + k] = (f16)h1;                                      \
        if ((t & 63) == 0) {                                                \
            fp_[0][(Q) ^ 1][w] = f0;                                        \
            fp_[1][(Q) ^ 1][w] = f1;                                        \
        }                                                                   \
        bar_cell();   /* single barrier: publishes state + staged weights */\
    }

    // prologue: stage cell 0, scalars for cell 0, then publish
    STAGE(0, 0);
    LOADF(0, bvA, wvA);
    asm volatile("s_waitcnt vmcnt(0)" ::: "memory");
    __syncthreads();

    for (int s = 0; s < NCELL; s += 2) {
        STAGE(s + 1, 1);              // buf1's prior readers done (barrier s-1)
        LOADF(s + 1, bvB, wvB);
        PROCESS(s, 0, bvA, wvA);      // reads buf0; barrier publishes buf1
        if (s + 2 < NCELL) {
            STAGE(s + 2, 0);          // buf0's readers done at PROCESS(s) barrier
            LOADF(s + 2, bvA, wvA);
        }
        PROCESS(s + 1, 1, bvB, wvB);  // reads buf1; barrier publishes buf0
    }
#undef STAGE
#undef LOADF
#undef PROCESS

    // tail: lp for cell 1023 (fp_ parity 0, published by the final barrier)
    if ((t & 63) == 4) {
        const int e_ = w >> 1, r_ = w & 1;
        const int cp_ = cell_of(NCELL - 1);
        const float z_ = fp_[e_][0][0] + fp_[e_][0][1]
                       + fp_[e_][0][2] + fp_[e_][0][3] + bfs[cp_];
        const float xh_ = 1.f / (1.f + __expf(-z_));
        const float m_ = smp2[e_][cp_];
        lp += (r_ == 0) ? __logf(xh_ + NEPS) * m_
                        : __logf(1.f - xh_ + NEPS) * (1.f - m_);
        lpb[w] = lp;
    }
    __syncthreads();
    if (t == 0) {
        out[b0]     = lpb[0] + lpb[1];
        out[b0 + 1] = lpb[2] + lpb[3];
    }
}

extern "C" void kernel_launch(void* const* d_in, const int* in_sizes, int n_in,
                              void* d_out, int out_size, void* d_ws, size_t ws_size,
                              hipStream_t stream) {
    const float* samples = (const float*)d_in[0];
    const float* W1      = (const float*)d_in[1];
    const float* b1      = (const float*)d_in[2];
    const float* Wf      = (const float*)d_in[3];
    const float* bf      = (const float*)d_in[4];
    float* outp = (float*)d_out;
    h2* Wt = (h2*)d_ws;   // 1024 * 8448 * 4B = 34.6 MB

    transpose_w<<<1024, 256, 0, stream>>>(W1, Wt);
    rnn2d<<<256, 256, 0, stream>>>(samples, Wt, b1, Wf, bf, outp);
}

// Round 4
// 1056.146 us; speedup vs baseline: 1.5106x; 1.5106x over previous
//
#include <hip/hip_runtime.h>
#include <math.h>
#include <stdint.h>

#define Lr 32
#define Hh 128
#define NCELL (Lr * Lr)
#define NEPS 1e-8f
#define CELLB 33792            // bytes per cell image: 32KB pair-chunks + 1KB tail

typedef _Float16 f16;
typedef f16 h2 __attribute__((ext_vector_type(2)));
typedef uint32_t u32;
typedef u32 u32x4 __attribute__((ext_vector_type(4)));
typedef u32 u32x2 __attribute__((ext_vector_type(2)));

// LDS-publish barrier (does NOT touch vmcnt: in-flight weight loads survive).
__device__ __forceinline__ void bar_lds() {
    asm volatile("s_waitcnt lgkmcnt(0)\n\ts_barrier" ::: "memory");
}

template<int CTRL>
__device__ __forceinline__ float dpp_get(float x) {
    return __int_as_float(__builtin_amdgcn_update_dpp(
        0, __float_as_int(x), CTRL, 0xf, 0xf, true));
}
// 0xB1 = quad_perm[1,0,3,2] (xor1), 0x4E = quad_perm[2,3,0,1] (xor2),
// 0x141 = row_half_mirror, 0x140 = row_mirror

__device__ __forceinline__ float rlane(float x, int l) {
    return __int_as_float(__builtin_amdgcn_readlane(__float_as_int(x), l));
}

__device__ __forceinline__ float dot2(h2 a, h2 b, float c) {
    return __builtin_amdgcn_fdot2(a, b, c, false);   // v_dot2_f32_f16
}

__device__ __forceinline__ h2 bch2(u32 v) {
    union { u32 u; h2 h; } cv; cv.u = v; return cv.h;
}
__device__ __forceinline__ float h16(u32 w, int hi) {
    union { unsigned short u; f16 h; } c;
    c.u = (unsigned short)(hi ? (w >> 16) : (w & 0xffff));
    return (float)c.h;
}

__device__ __forceinline__ float fast_tanh(float x) {
    x = fminf(9.f, fmaxf(-9.f, x));
    const float e = __expf(2.f * x);
    return 1.f - 2.f / (e + 1.f);
}

__device__ __forceinline__ int cell_of(int s) {
    const int i = s >> 5, jj = s & 31;
    const int c = (i & 1) ? (Lr - 1 - jj) : jj;
    return i * Lr + c;
}

// W1[cell][k][m] (fp32, k<128, m<130) -> per-cell 33KB image:
//  chunk region (32KB): [q4<8][t<256] 16B = 4 f16-pairs; thread t (k=t>>1,
//    half=t&1) owns h-pairs p = half*32+q4*4+{0..3} = W cols (2+2p, 3+2p).
//    -> rnn ISSUE is 8 fully-coalesced dwordx4 per thread.
//  tail region (1KB): [k<128] 8B = f16 {sp0,sp1,sp2,wf}:
//    spins are binary, so spin-cols + bias fold to 3 candidates:
//    sp0=2W[k][1]+2b[k] (xh+xv=0), sp1=W[k][0]+W[k][1]+2b[k], sp2=2W[k][0]+2b[k].
__global__ __launch_bounds__(256)
void transpose_w(const float* __restrict__ W1, const float* __restrict__ b1,
                 const float* __restrict__ Wf, char* __restrict__ Wt) {
    __shared__ float tile[Hh * 130];    // 66.6 KB
    const int cell = blockIdx.x;
    const float* src = W1 + (size_t)cell * (Hh * 130);
    for (int idx = threadIdx.x; idx < Hh * 130; idx += 256)
        tile[idx] = src[idx];
    __syncthreads();
    char* dst = Wt + (size_t)cell * CELLB;
    const int t = threadIdx.x, kk = t >> 1, hf = t & 1;
    for (int q4 = 0; q4 < 8; ++q4) {
        union { u32x4 v; f16 h[8]; } o;
        for (int j = 0; j < 4; ++j) {
            const int p = hf * 32 + q4 * 4 + j;
            o.h[2 * j]     = (f16)tile[kk * 130 + 2 + 2 * p];
            o.h[2 * j + 1] = (f16)tile[kk * 130 + 3 + 2 * p];
        }
        *(u32x4*)(dst + q4 * 4096 + t * 16) = o.v;
    }
    if (t < Hh) {
        union { u32x2 v; f16 h[4]; } o;
        const float w0 = tile[t * 130 + 0], w1 = tile[t * 130 + 1];
        const float bb = 2.f * b1[cell * Hh + t];
        o.h[0] = (f16)(2.f * w1 + bb);
        o.h[1] = (f16)(w0 + w1 + bb);
        o.h[2] = (f16)(2.f * w0 + bb);
        o.h[3] = (f16)Wf[cell * Hh + t];
        *(u32x2*)(dst + 32768 + t * 8) = o.v;
    }
}

// 256 blocks x 2 batch elements, 1 block/CU, 4 waves. Lane pair (2k,2k+1)
// owns output k; half=t&1 splits the 64-pair hidden dot. Weights live in
// FOUR rotating register buffers filled by asm-volatile global loads
// (un-sinkable, un-spillable by construction) 2 cells ahead; the per-cell
// wait is a counted vmcnt(18) (= 2 stages x 9 uniform loads in flight),
// never a drain -> LLC latency fully covered. No LDS weight traffic.
__global__ __launch_bounds__(256, 1)
void rnn2d(const float* __restrict__ samples,
           const char* __restrict__ Wt,
           const float* __restrict__ bfv,
           float* __restrict__ out)
{
    __shared__ __align__(16) h2  inp[2][2][64];     // 64 pairs/elem, dbuffered
    __shared__ __align__(16) f16 hvh[2][Lr * Hh];   // vertical hidden, 16 KB
    __shared__ float smp2[2][NCELL];
    __shared__ float bfs[NCELL];
    __shared__ float fp_[2][2][4];                  // head partials [e][par][wave]
    __shared__ int   sidx[2][2];                    // spin-case 0/1/2 [e][par]
    __shared__ float lpb[4];

    const int t    = threadIdx.x;
    const int k    = t >> 1;
    const int half = t & 1;
    const int w    = t >> 6;
    const int b0   = blockIdx.x * 2;

    // loop-invariant load offsets (VGPRs)
    u32 vc[8], vt;
    for (int q4 = 0; q4 < 8; ++q4) vc[q4] = (u32)(q4 * 4096 + t * 16);
    vt = (u32)(32768 + k * 8);

    {
        f16* z1 = (f16*)inp;
        for (int idx = t; idx < 2 * 2 * 64 * 2; idx += 256) z1[idx] = (f16)0.f;
        f16* z2 = (f16*)hvh;
        for (int idx = t; idx < 2 * Lr * Hh; idx += 256) z2[idx] = (f16)0.f;
        for (int idx = t; idx < NCELL; idx += 256) {
            smp2[0][idx] = samples[(size_t)b0 * NCELL + idx];
            smp2[1][idx] = samples[(size_t)(b0 + 1) * NCELL + idx];
            bfs[idx] = bfv[idx];
        }
        if (t == 0) { sidx[0][0] = 0; sidx[1][0] = 0; }   // cell 0: xh=xv=0
    }
    float lp = 0.f;

    u32x4 A0,A1,A2,A3,A4,A5,A6,A7, B0,B1,B2,B3,B4,B5,B6,B7;
    u32x4 C0,C1,C2,C3,C4,C5,C6,C7, D0,D1,D2,D3,D4,D5,D6,D7;
    u32x2 TA, TB, TC, TD;

// issue the 9 uniform volatile loads for cell S into one register buffer
#define ISSUE(S, W0,W1_,W2_,W3_,W4_,W5_,W6_,W7_, TT)                        \
    {                                                                       \
        const int s_ = ((S) < NCELL) ? (S) : 0;   /* uniform dummy at tail */\
        const char* cb_ = Wt + (size_t)cell_of(s_) * CELLB;                 \
        asm volatile("global_load_dwordx4 %0, %1, %2" : "=v"(W0)  : "v"(vc[0]), "s"(cb_)); \
        asm volatile("global_load_dwordx4 %0, %1, %2" : "=v"(W1_) : "v"(vc[1]), "s"(cb_)); \
        asm volatile("global_load_dwordx4 %0, %1, %2" : "=v"(W2_) : "v"(vc[2]), "s"(cb_)); \
        asm volatile("global_load_dwordx4 %0, %1, %2" : "=v"(W3_) : "v"(vc[3]), "s"(cb_)); \
        asm volatile("global_load_dwordx4 %0, %1, %2" : "=v"(W4_) : "v"(vc[4]), "s"(cb_)); \
        asm volatile("global_load_dwordx4 %0, %1, %2" : "=v"(W5_) : "v"(vc[5]), "s"(cb_)); \
        asm volatile("global_load_dwordx4 %0, %1, %2" : "=v"(W6_) : "v"(vc[6]), "s"(cb_)); \
        asm volatile("global_load_dwordx4 %0, %1, %2" : "=v"(W7_) : "v"(vc[7]), "s"(cb_)); \
        asm volatile("global_load_dwordx2 %0, %1, %2" : "=v"(TT)  : "v"(vt),    "s"(cb_)); \
    }

// counted wait: retire everything except the newest 2 stages (2 x 9 ops)
#define WAITP()                                                             \
    asm volatile("s_waitcnt vmcnt(18)" ::: "memory");                       \
    __builtin_amdgcn_sched_barrier(0);

#define DOT4(WQ, QQ, Q4)                                                    \
    {                                                                       \
        const u32x4 v_ = (WQ);                                              \
        const uint4 xa_ = *(const uint4*)&inp[0][QQ][half * 32 + (Q4) * 4]; \
        const uint4 xb_ = *(const uint4*)&inp[1][QQ][half * 32 + (Q4) * 4]; \
        a00 = dot2(bch2(v_.x), bch2(xa_.x), a00);                           \
        a10 = dot2(bch2(v_.x), bch2(xb_.x), a10);                           \
        a01 = dot2(bch2(v_.y), bch2(xa_.y), a01);                           \
        a11 = dot2(bch2(v_.y), bch2(xb_.y), a11);                           \
        a02 = dot2(bch2(v_.z), bch2(xa_.z), a02);                           \
        a12 = dot2(bch2(v_.z), bch2(xb_.z), a12);                           \
        a03 = dot2(bch2(v_.w), bch2(xa_.w), a03);                           \
        a13 = dot2(bch2(v_.w), bch2(xb_.w), a13);                           \
    }

#define PROC(S, Q, W0,W1_,W2_,W3_,W4_,W5_,W6_,W7_, TT)                      \
    {                                                                       \
        const int i_ = (S) >> 5, j_ = (S) & 31;                             \
        const int c_ = (i_ & 1) ? (Lr - 1 - j_) : j_;                       \
        const int sn_ = ((S) + 1 < NCELL) ? (S) + 1 : (S);                  \
        const int in_ = sn_ >> 5, jn_ = sn_ & 31;                           \
        const int cn_ = (in_ & 1) ? (Lr - 1 - jn_) : jn_;                   \
        const float hvn0 = (float)hvh[0][cn_ * Hh + k];                     \
        const float hvn1 = (float)hvh[1][cn_ * Hh + k];                     \
        /* deferred lp tail for cell S-1: one lane per wave, one log each */\
        if (((t & 63) == 4) && (S) > 0) {                                   \
            const int e_ = w >> 1, r_ = w & 1;                              \
            const int cp_ = cell_of((S) - 1);                               \
            const float z_ = fp_[e_][Q][0] + fp_[e_][Q][1]                  \
                           + fp_[e_][Q][2] + fp_[e_][Q][3] + bfs[cp_];      \
            const float xh_ = 1.f / (1.f + __expf(-z_));                    \
            const float m_ = smp2[e_][cp_];                                 \
            lp += (r_ == 0) ? __logf(xh_ + NEPS) * m_                       \
                            : __logf(1.f - xh_ + NEPS) * (1.f - m_);        \
        }                                                                   \
        /* 64-pair hidden dot from register weights + broadcast LDS input */\
        float a00=0.f,a01=0.f,a02=0.f,a03=0.f;                              \
        float a10=0.f,a11=0.f,a12=0.f,a13=0.f;                              \
        DOT4(W0,  Q, 0) DOT4(W1_, Q, 1)                                     \
        DOT4(W2_, Q, 2) DOT4(W3_, Q, 3)                                     \
        DOT4(W4_, Q, 4) DOT4(W5_, Q, 5)                                     \
        DOT4(W6_, Q, 6) DOT4(W7_, Q, 7)                                     \
        /* spin-case + folded bias (half 0 adds; combine spreads to both) */\
        const int sx0 = sidx[0][Q], sx1 = sidx[1][Q];                       \
        const float t0_ = h16(TT.x, 0), t1_ = h16(TT.x, 1);                 \
        const float t2_ = h16(TT.y, 0), wfv = h16(TT.y, 1);                 \
        float sp0 = (sx0 == 2) ? t2_ : ((sx0 == 1) ? t1_ : t0_);            \
        float sp1 = (sx1 == 2) ? t2_ : ((sx1 == 1) ? t1_ : t0_);            \
        if (half) { sp0 = 0.f; sp1 = 0.f; }                                 \
        float s0 = ((a00 + a01) + (a02 + a03)) + sp0;                       \
        float s1 = ((a10 + a11) + (a12 + a13)) + sp1;                       \
        s0 += dpp_get<0xB1>(s0);   /* pair combine: full dot + spin+bias */ \
        s1 += dpp_get<0xB1>(s1);                                            \
        const float h0 = fast_tanh(s0);                                     \
        const float h1 = fast_tanh(s1);                                     \
        /* head: per-wave sum of h[k]*wf[k] (pair-duplicated, skip xor1) */ \
        float f0 = h0 * wfv, f1 = h1 * wfv;                                 \
        f0 += dpp_get<0x4E>(f0);  f1 += dpp_get<0x4E>(f1);                  \
        f0 += dpp_get<0x141>(f0); f1 += dpp_get<0x141>(f1);                 \
        f0 += dpp_get<0x140>(f0); f1 += dpp_get<0x140>(f1);                 \
        f0 = f0 + rlane(f0, 16) + rlane(f0, 32) + rlane(f0, 48);            \
        f1 = f1 + rlane(f1, 16) + rlane(f1, 32) + rlane(f1, 48);            \
        if ((S) + 1 < NCELL) {                                              \
            const float v0 = ((jn_ == 0) ? 0.f : h0)                        \
                           + ((cn_ == c_) ? h0 : hvn0);                     \
            const float v1 = ((jn_ == 0) ? 0.f : h1)                        \
                           + ((cn_ == c_) ? h1 : hvn1);                     \
            const float v0p = dpp_get<0x4E>(v0);  /* partner k's value */   \
            const float v1p = dpp_get<0x4E>(v1);                            \
            if ((t & 3) == 0) {                                             \
                h2 u0; u0.x = (f16)v0; u0.y = (f16)v0p;                     \
                h2 u1; u1.x = (f16)v1; u1.y = (f16)v1p;                     \
                inp[0][(Q) ^ 1][t >> 2] = u0;                               \
                inp[1][(Q) ^ 1][t >> 2] = u1;                               \
            }                                                               \
            if (t == 0) {                                                   \
                const float xh0 = (jn_ == 0) ? 0.f : smp2[0][i_ * Lr + c_]; \
                const float xv0 = (in_ == 0) ? 0.f                          \
                                             : smp2[0][(in_ - 1) * Lr + cn_]; \
                const float xh1 = (jn_ == 0) ? 0.f : smp2[1][i_ * Lr + c_]; \
                const float xv1 = (in_ == 0) ? 0.f                          \
                                             : smp2[1][(in_ - 1) * Lr + cn_]; \
                sidx[0][(Q) ^ 1] = (int)(xh0 + xv0);                        \
                sidx[1][(Q) ^ 1] = (int)(xh1 + xv1);                        \
            }                                                               \
        }                                                                   \
        hvh[0][c_ * Hh + k] = (f16)h0;  /* k-partitioned: race-free */      \
        hvh[1][c_ * Hh + k] = (f16)h1;                                      \
        if ((t & 63) == 0) {                                                \
            fp_[0][(Q) ^ 1][w] = f0;                                        \
            fp_[1][(Q) ^ 1][w] = f1;                                        \
        }                                                                   \
        bar_lds();   /* single LDS barrier per cell; vmcnt untouched */     \
    }

    // prologue: buffers for cells 0 and 1 in flight; first in-loop WAITP
    // (vmcnt 18 = B1's 9 + C's 9) guarantees buffer A (cell 0) has landed.
    ISSUE(0, A0,A1,A2,A3,A4,A5,A6,A7, TA);
    ISSUE(1, B0,B1,B2,B3,B4,B5,B6,B7, TB);
    __syncthreads();

    for (int s = 0; s < NCELL; s += 4) {
        ISSUE(s + 2, C0,C1,C2,C3,C4,C5,C6,C7, TC); WAITP();
        PROC(s,     0, A0,A1,A2,A3,A4,A5,A6,A7, TA);
        ISSUE(s + 3, D0,D1,D2,D3,D4,D5,D6,D7, TD); WAITP();
        PROC(s + 1, 1, B0,B1,B2,B3,B4,B5,B6,B7, TB);
        ISSUE(s + 4, A0,A1,A2,A3,A4,A5,A6,A7, TA); WAITP();
        PROC(s + 2, 0, C0,C1,C2,C3,C4,C5,C6,C7, TC);
        ISSUE(s + 5, B0,B1,B2,B3,B4,B5,B6,B7, TB); WAITP();
        PROC(s + 3, 1, D0,D1,D2,D3,D4,D5,D6,D7, TD);
    }
#undef ISSUE
#undef WAITP
#undef DOT4
#undef PROC

    // tail: lp for cell 1023 (fp_ parity 0, published by the final barrier)
    if ((t & 63) == 4) {
        const int e_ = w >> 1, r_ = w & 1;
        const int cp_ = cell_of(NCELL - 1);
        const float z_ = fp_[e_][0][0] + fp_[e_][0][1]
                       + fp_[e_][0][2] + fp_[e_][0][3] + bfs[cp_];
        const float xh_ = 1.f / (1.f + __expf(-z_));
        const float m_ = smp2[e_][cp_];
        lp += (r_ == 0) ? __logf(xh_ + NEPS) * m_
                        : __logf(1.f - xh_ + NEPS) * (1.f - m_);
        lpb[w] = lp;
    }
    __syncthreads();
    if (t == 0) {
        out[b0]     = lpb[0] + lpb[1];
        out[b0 + 1] = lpb[2] + lpb[3];
    }
}

extern "C" void kernel_launch(void* const* d_in, const int* in_sizes, int n_in,
                              void* d_out, int out_size, void* d_ws, size_t ws_size,
                              hipStream_t stream) {
    const float* samples = (const float*)d_in[0];
    const float* W1      = (const float*)d_in[1];
    const float* b1      = (const float*)d_in[2];
    const float* Wf      = (const float*)d_in[3];
    const float* bf      = (const float*)d_in[4];
    float* outp = (float*)d_out;
    char* Wt = (char*)d_ws;   // 1024 * 33792 B = 34.6 MB (same as before)

    transpose_w<<<1024, 256, 0, stream>>>(W1, b1, Wf, Wt);
    rnn2d<<<256, 256, 0, stream>>>(samples, Wt, bf, outp);
}

// Round 5
// 960.388 us; speedup vs baseline: 1.6612x; 1.0997x over previous
//
#include <hip/hip_runtime.h>
#include <math.h>
#include <stdint.h>

#define Lr 32
#define Hh 128
#define NCELL (Lr * Lr)
#define NEPS 1e-8f
#define CELLB 33792            // bytes per cell image: 32KB pair-chunks + 1KB tail

typedef _Float16 f16;
typedef f16 h2 __attribute__((ext_vector_type(2)));
typedef uint32_t u32;
typedef u32 u32x4 __attribute__((ext_vector_type(4)));
typedef u32 u32x2 __attribute__((ext_vector_type(2)));

// LDS-publish barrier (does NOT touch vmcnt: in-flight weight loads survive).
__device__ __forceinline__ void bar_lds() {
    asm volatile("s_waitcnt lgkmcnt(0)\n\ts_barrier" ::: "memory");
}

template<int CTRL>
__device__ __forceinline__ float dpp_get(float x) {
    return __int_as_float(__builtin_amdgcn_update_dpp(
        0, __float_as_int(x), CTRL, 0xf, 0xf, true));
}
// 0xB1 = quad_perm[1,0,3,2] (xor1), 0x4E = quad_perm[2,3,0,1] (xor2),
// 0x141 = row_half_mirror, 0x140 = row_mirror

__device__ __forceinline__ float rlane(float x, int l) {
    return __int_as_float(__builtin_amdgcn_readlane(__float_as_int(x), l));
}

__device__ __forceinline__ float dot2(h2 a, h2 b, float c) {
    return __builtin_amdgcn_fdot2(a, b, c, false);   // v_dot2_f32_f16
}

__device__ __forceinline__ h2 bch2(u32 v) {
    union { u32 u; h2 h; } cv; cv.u = v; return cv.h;
}
__device__ __forceinline__ float h16(u32 w, int hi) {
    union { unsigned short u; f16 h; } c;
    c.u = (unsigned short)(hi ? (w >> 16) : (w & 0xffff));
    return (float)c.h;
}

__device__ __forceinline__ float fast_tanh(float x) {
    x = fminf(9.f, fmaxf(-9.f, x));
    const float e = __expf(2.f * x);
    return 1.f - 2.f / (e + 1.f);
}

__device__ __forceinline__ int cell_of(int s) {
    const int i = s >> 5, jj = s & 31;
    const int c = (i & 1) ? (Lr - 1 - jj) : jj;
    return i * Lr + c;
}

// W1[cell][k][m] (fp32, k<128, m<130) -> per-cell 33KB image:
//  chunk region (32KB): [q4<8][t<256] 16B = 4 f16-pairs; thread t (k=t>>1,
//    half=t&1) owns h-pairs p = half*32+q4*4+{0..3} = W cols (2+2p, 3+2p).
//    -> rnn ISSUE is 8 fully-coalesced dwordx4 per thread.
//  tail region (1KB): [k<128] 8B = f16 {sp0,sp1,sp2,wf}:
//    spins are binary, so spin-cols + bias fold to 3 candidates:
//    sp0=2W[k][1]+2b[k] (xh+xv=0), sp1=W[k][0]+W[k][1]+2b[k], sp2=2W[k][0]+2b[k].
__global__ __launch_bounds__(256)
void transpose_w(const float* __restrict__ W1, const float* __restrict__ b1,
                 const float* __restrict__ Wf, char* __restrict__ Wt) {
    __shared__ float tile[Hh * 130];    // 66.6 KB
    const int cell = blockIdx.x;
    const float* src = W1 + (size_t)cell * (Hh * 130);
    for (int idx = threadIdx.x; idx < Hh * 130; idx += 256)
        tile[idx] = src[idx];
    __syncthreads();
    char* dst = Wt + (size_t)cell * CELLB;
    const int t = threadIdx.x, kk = t >> 1, hf = t & 1;
    for (int q4 = 0; q4 < 8; ++q4) {
        union { u32x4 v; f16 h[8]; } o;
        for (int j = 0; j < 4; ++j) {
            const int p = hf * 32 + q4 * 4 + j;
            o.h[2 * j]     = (f16)tile[kk * 130 + 2 + 2 * p];
            o.h[2 * j + 1] = (f16)tile[kk * 130 + 3 + 2 * p];
        }
        *(u32x4*)(dst + q4 * 4096 + t * 16) = o.v;
    }
    if (t < Hh) {
        union { u32x2 v; f16 h[4]; } o;
        const float w0 = tile[t * 130 + 0], w1 = tile[t * 130 + 1];
        const float bb = 2.f * b1[cell * Hh + t];
        o.h[0] = (f16)(2.f * w1 + bb);
        o.h[1] = (f16)(w0 + w1 + bb);
        o.h[2] = (f16)(2.f * w0 + bb);
        o.h[3] = (f16)Wf[cell * Hh + t];
        *(u32x2*)(dst + 32768 + t * 8) = o.v;
    }
}

// 512 blocks x 1 batch element, 2 blocks/CU (independent barriers -> the two
// blocks' VMEM / LDS / VALU phases interleave, breaking the 4-wave phase
// convoy measured in round 4: all pipes <40% busy at 1 block/CU). Per-thread
// work halves (32 dot2/cell). Co-resident blocks read the same weight stream
// nearly in phase -> trailing block hits L1/L2, LLC traffic ~unchanged.
// Weights in FOUR rotating register buffers via asm-volatile loads, counted
// vmcnt(18) retirement (never a drain), no LDS weight traffic.
__global__ __launch_bounds__(256, 2)
void rnn2d(const float* __restrict__ samples,
           const char* __restrict__ Wt,
           const float* __restrict__ bfv,
           float* __restrict__ out)
{
    __shared__ __align__(16) h2  inp[2][64];        // input pairs, dbuffered
    __shared__ __align__(16) f16 hvh[Lr * Hh];      // vertical hidden, 8 KB
    __shared__ float smp[NCELL];
    __shared__ float bfs[NCELL];
    __shared__ float fp_[2][4];                     // head partials [parity][wave]
    __shared__ int   sidx[2];                       // spin-case 0/1/2 [parity]
    __shared__ float lpb[2];

    const int t    = threadIdx.x;
    const int k    = t >> 1;
    const int half = t & 1;
    const int w    = t >> 6;
    const int b    = blockIdx.x;

    // loop-invariant load offsets (VGPRs)
    u32 vc[8], vt;
    for (int q4 = 0; q4 < 8; ++q4) vc[q4] = (u32)(q4 * 4096 + t * 16);
    vt = (u32)(32768 + k * 8);

    {
        f16* z1 = (f16*)inp;
        for (int idx = t; idx < 2 * 64 * 2; idx += 256) z1[idx] = (f16)0.f;
        f16* z2 = (f16*)hvh;
        for (int idx = t; idx < Lr * Hh; idx += 256) z2[idx] = (f16)0.f;
        for (int idx = t; idx < NCELL; idx += 256) {
            smp[idx] = samples[(size_t)b * NCELL + idx];
            bfs[idx] = bfv[idx];
        }
        if (t == 0) sidx[0] = 0;      // cell 0: xh=xv=0
    }
    float lp = 0.f;

    u32x4 A0,A1,A2,A3,A4,A5,A6,A7, B0,B1,B2,B3,B4,B5,B6,B7;
    u32x4 C0,C1,C2,C3,C4,C5,C6,C7, D0,D1,D2,D3,D4,D5,D6,D7;
    u32x2 TA, TB, TC, TD;

// issue the 9 uniform volatile loads for cell S into one register buffer
#define ISSUE(S, W0,W1_,W2_,W3_,W4_,W5_,W6_,W7_, TT)                        \
    {                                                                       \
        const int s_ = ((S) < NCELL) ? (S) : 0;   /* uniform dummy at tail */\
        const char* cb_ = Wt + (size_t)cell_of(s_) * CELLB;                 \
        asm volatile("global_load_dwordx4 %0, %1, %2" : "=v"(W0)  : "v"(vc[0]), "s"(cb_)); \
        asm volatile("global_load_dwordx4 %0, %1, %2" : "=v"(W1_) : "v"(vc[1]), "s"(cb_)); \
        asm volatile("global_load_dwordx4 %0, %1, %2" : "=v"(W2_) : "v"(vc[2]), "s"(cb_)); \
        asm volatile("global_load_dwordx4 %0, %1, %2" : "=v"(W3_) : "v"(vc[3]), "s"(cb_)); \
        asm volatile("global_load_dwordx4 %0, %1, %2" : "=v"(W4_) : "v"(vc[4]), "s"(cb_)); \
        asm volatile("global_load_dwordx4 %0, %1, %2" : "=v"(W5_) : "v"(vc[5]), "s"(cb_)); \
        asm volatile("global_load_dwordx4 %0, %1, %2" : "=v"(W6_) : "v"(vc[6]), "s"(cb_)); \
        asm volatile("global_load_dwordx4 %0, %1, %2" : "=v"(W7_) : "v"(vc[7]), "s"(cb_)); \
        asm volatile("global_load_dwordx2 %0, %1, %2" : "=v"(TT)  : "v"(vt),    "s"(cb_)); \
    }

// counted wait: retire everything except the newest 2 stages (2 x 9 ops)
#define WAITP()                                                             \
    asm volatile("s_waitcnt vmcnt(18)" ::: "memory");                       \
    __builtin_amdgcn_sched_barrier(0);

#define DOT4(WQ, QQ, Q4)                                                    \
    {                                                                       \
        const u32x4 v_ = (WQ);                                              \
        const uint4 xa_ = *(const uint4*)&inp[QQ][half * 32 + (Q4) * 4];    \
        a00 = dot2(bch2(v_.x), bch2(xa_.x), a00);                           \
        a01 = dot2(bch2(v_.y), bch2(xa_.y), a01);                           \
        a02 = dot2(bch2(v_.z), bch2(xa_.z), a02);                           \
        a03 = dot2(bch2(v_.w), bch2(xa_.w), a03);                           \
    }

#define PROC(S, Q, W0,W1_,W2_,W3_,W4_,W5_,W6_,W7_, TT)                      \
    {                                                                       \
        const int i_ = (S) >> 5, j_ = (S) & 31;                             \
        const int c_ = (i_ & 1) ? (Lr - 1 - j_) : j_;                       \
        const int sn_ = ((S) + 1 < NCELL) ? (S) + 1 : (S);                  \
        const int in_ = sn_ >> 5, jn_ = sn_ & 31;                           \
        const int cn_ = (in_ & 1) ? (Lr - 1 - jn_) : jn_;                   \
        const float hvn = (float)hvh[cn_ * Hh + k];                         \
        /* deferred lp tail for cell S-1: lane 4 of waves 0/1, one log each */\
        if (((t & 63) == 4) && (w < 2) && (S) > 0) {                        \
            const int cp_ = cell_of((S) - 1);                               \
            const float z_ = fp_[Q][0] + fp_[Q][1]                          \
                           + fp_[Q][2] + fp_[Q][3] + bfs[cp_];              \
            const float xh_ = 1.f / (1.f + __expf(-z_));                    \
            const float m_ = smp[cp_];                                      \
            lp += (w == 0) ? __logf(xh_ + NEPS) * m_                        \
                           : __logf(1.f - xh_ + NEPS) * (1.f - m_);         \
        }                                                                   \
        /* 32-pair hidden half-dot: register weights x broadcast LDS input */\
        float a00=0.f,a01=0.f,a02=0.f,a03=0.f;                              \
        DOT4(W0,  Q, 0) DOT4(W1_, Q, 1)                                     \
        DOT4(W2_, Q, 2) DOT4(W3_, Q, 3)                                     \
        DOT4(W4_, Q, 4) DOT4(W5_, Q, 5)                                     \
        DOT4(W6_, Q, 6) DOT4(W7_, Q, 7)                                     \
        /* spin-case + folded bias (half 0 adds; combine spreads to both) */\
        const int sx = sidx[Q];                                             \
        const float t0_ = h16(TT.x, 0), t1_ = h16(TT.x, 1);                 \
        const float t2_ = h16(TT.y, 0), wfv = h16(TT.y, 1);                 \
        float sp = (sx == 2) ? t2_ : ((sx == 1) ? t1_ : t0_);               \
        if (half) sp = 0.f;                                                 \
        float s0 = ((a00 + a01) + (a02 + a03)) + sp;                        \
        s0 += dpp_get<0xB1>(s0);   /* pair combine: full dot + spin+bias */ \
        const float h0 = fast_tanh(s0);                                     \
        /* head: per-wave sum of h[k]*wf[k] (pair-duplicated, skip xor1) */ \
        float f0 = h0 * wfv;                                                \
        f0 += dpp_get<0x4E>(f0);                                            \
        f0 += dpp_get<0x141>(f0);                                           \
        f0 += dpp_get<0x140>(f0);                                           \
        f0 = f0 + rlane(f0, 16) + rlane(f0, 32) + rlane(f0, 48);            \
        if ((S) + 1 < NCELL) {                                              \
            const float v0 = ((jn_ == 0) ? 0.f : h0)                        \
                           + ((cn_ == c_) ? h0 : hvn);                      \
            const float v0p = dpp_get<0x4E>(v0);  /* partner k's value */   \
            if ((t & 3) == 0) {                                             \
                h2 u0; u0.x = (f16)v0; u0.y = (f16)v0p;                     \
                inp[(Q) ^ 1][t >> 2] = u0;                                  \
            }                                                               \
            if (t == 0) {                                                   \
                const float xh0 = (jn_ == 0) ? 0.f : smp[i_ * Lr + c_];     \
                const float xv0 = (in_ == 0) ? 0.f                          \
                                             : smp[(in_ - 1) * Lr + cn_];   \
                sidx[(Q) ^ 1] = (int)(xh0 + xv0);                           \
            }                                                               \
        }                                                                   \
        hvh[c_ * Hh + k] = (f16)h0;     /* k-partitioned: race-free */      \
        if ((t & 63) == 0) fp_[(Q) ^ 1][w] = f0;                            \
        bar_lds();   /* single LDS barrier per cell; vmcnt untouched */     \
    }

    // prologue: buffers for cells 0 and 1 in flight; first in-loop WAITP
    // (vmcnt 18 = B's 9 + C's 9) guarantees buffer A (cell 0) has landed.
    ISSUE(0, A0,A1,A2,A3,A4,A5,A6,A7, TA);
    ISSUE(1, B0,B1,B2,B3,B4,B5,B6,B7, TB);
    __syncthreads();

    for (int s = 0; s < NCELL; s += 4) {
        ISSUE(s + 2, C0,C1,C2,C3,C4,C5,C6,C7, TC); WAITP();
        PROC(s,     0, A0,A1,A2,A3,A4,A5,A6,A7, TA);
        ISSUE(s + 3, D0,D1,D2,D3,D4,D5,D6,D7, TD); WAITP();
        PROC(s + 1, 1, B0,B1,B2,B3,B4,B5,B6,B7, TB);
        ISSUE(s + 4, A0,A1,A2,A3,A4,A5,A6,A7, TA); WAITP();
        PROC(s + 2, 0, C0,C1,C2,C3,C4,C5,C6,C7, TC);
        ISSUE(s + 5, B0,B1,B2,B3,B4,B5,B6,B7, TB); WAITP();
        PROC(s + 3, 1, D0,D1,D2,D3,D4,D5,D6,D7, TD);
    }
#undef ISSUE
#undef WAITP
#undef DOT4
#undef PROC

    // tail: lp for cell 1023 (fp_ parity 0, published by the final barrier)
    if (((t & 63) == 4) && (w < 2)) {
        const int cp_ = cell_of(NCELL - 1);
        const float z_ = fp_[0][0] + fp_[0][1] + fp_[0][2] + fp_[0][3]
                       + bfs[cp_];
        const float xh_ = 1.f / (1.f + __expf(-z_));
        const float m_ = smp[cp_];
        lp += (w == 0) ? __logf(xh_ + NEPS) * m_
                       : __logf(1.f - xh_ + NEPS) * (1.f - m_);
        lpb[w] = lp;
    }
    __syncthreads();
    if (t == 0) out[b] = lpb[0] + lpb[1];
}

extern "C" void kernel_launch(void* const* d_in, const int* in_sizes, int n_in,
                              void* d_out, int out_size, void* d_ws, size_t ws_size,
                              hipStream_t stream) {
    const float* samples = (const float*)d_in[0];
    const float* W1      = (const float*)d_in[1];
    const float* b1      = (const float*)d_in[2];
    const float* Wf      = (const float*)d_in[3];
    const float* bf      = (const float*)d_in[4];
    float* outp = (float*)d_out;
    char* Wt = (char*)d_ws;   // 1024 * 33792 B = 34.6 MB

    transpose_w<<<1024, 256, 0, stream>>>(W1, b1, Wf, Wt);
    rnn2d<<<512, 256, 0, stream>>>(samples, Wt, bf, outp);
}